// Round 1
// baseline (127.176 us; speedup 1.0000x reference)
//
#include <hip/hip_runtime.h>
#include <math.h>

// Problem constants (from reference)
#define B_    64
#define N_    2048
#define D_    512
#define C_    128
#define TOPK_ 8
#define LN_EPS_ 1e-5f

// ---------------------------------------------------------------------------
// Kernel 1: per-batch precompute.
//   cw[b][d] = ln_w[d] * W[d, y[b]]          (the effective score weight)
//   cb[b]    = sum_d ln_b[d]*W[d,y[b]] + bias[y[b]]
//   su[b]    = sum_d cw[b][d]
// score[b,n] = rstd * (dot(x, cw[b]) - mu * su[b]) + cb[b]
// ---------------------------------------------------------------------------
__global__ __launch_bounds__(256) void prep_kernel(
    const float* __restrict__ ln_w, const float* __restrict__ ln_b,
    const float* __restrict__ W, const float* __restrict__ bias,
    const int* __restrict__ y,
    float* __restrict__ cw, float* __restrict__ cb, float* __restrict__ su) {
  int b = blockIdx.x;
  int cls = y[b];
  __shared__ float red0[256];
  __shared__ float red1[256];
  float l0 = 0.f, l1 = 0.f;
  for (int d = threadIdx.x; d < D_; d += 256) {
    float wcol = W[d * C_ + cls];
    float u = ln_w[d] * wcol;
    cw[b * D_ + d] = u;
    l0 += ln_b[d] * wcol;
    l1 += u;
  }
  red0[threadIdx.x] = l0;
  red1[threadIdx.x] = l1;
  __syncthreads();
  for (int s = 128; s > 0; s >>= 1) {
    if (threadIdx.x < s) {
      red0[threadIdx.x] += red0[threadIdx.x + s];
      red1[threadIdx.x] += red1[threadIdx.x + s];
    }
    __syncthreads();
  }
  if (threadIdx.x == 0) {
    cb[b] = red0[0] + bias[cls];
    su[b] = red1[0];
  }
}

// ---------------------------------------------------------------------------
// Kernel 2 (HBM-bound, ~256 MB read): one wave per clip, fused single pass:
// sum(x), sum(x^2), dot(x, cw) -> masked score. float4 loads, shfl reduce.
// mask layout auto-detected (int32 / uint8 / float) via first word: since
// lengths >= TOPK the first 8 mask entries are all true.
// ---------------------------------------------------------------------------
__global__ __launch_bounds__(256) void score_kernel(
    const float* __restrict__ x, const float* __restrict__ cw,
    const float* __restrict__ cb, const float* __restrict__ su,
    const unsigned char* __restrict__ mask, float* __restrict__ score) {
  int wave = threadIdx.x >> 6;
  int lane = threadIdx.x & 63;
  int clip = blockIdx.x * 4 + wave;          // 0 .. B*N-1
  int b = clip >> 11;                        // clip / N_
  const float4* x4 = (const float4*)(x + (size_t)clip * D_);
  const float4* u4 = (const float4*)(cw + (size_t)b * D_);
  // 512 floats = 128 float4; lanes 0..63 cover [0,64) then [64,128)
  float4 xa = x4[lane];
  float4 xb = x4[lane + 64];
  float4 ua = u4[lane];
  float4 ub = u4[lane + 64];
  float s  = xa.x + xa.y + xa.z + xa.w + xb.x + xb.y + xb.z + xb.w;
  float sq = fmaf(xa.x, xa.x, fmaf(xa.y, xa.y, fmaf(xa.z, xa.z, xa.w * xa.w)))
           + fmaf(xb.x, xb.x, fmaf(xb.y, xb.y, fmaf(xb.z, xb.z, xb.w * xb.w)));
  float dt = fmaf(xa.x, ua.x, fmaf(xa.y, ua.y, fmaf(xa.z, ua.z, xa.w * ua.w)))
           + fmaf(xb.x, ub.x, fmaf(xb.y, ub.y, fmaf(xb.z, ub.z, xb.w * ub.w)));
  for (int off = 32; off > 0; off >>= 1) {
    s  += __shfl_xor(s, off);
    sq += __shfl_xor(sq, off);
    dt += __shfl_xor(dt, off);
  }
  if (lane == 0) {
    float mu = s * (1.f / D_);
    float var = sq * (1.f / D_) - mu * mu;
    float rstd = rsqrtf(var + LN_EPS_);
    float val = rstd * (dt - mu * su[b]) + cb[b];
    unsigned int tag = *(const unsigned int*)mask;
    bool valid;
    if (tag == 1u)               valid = ((const int*)mask)[clip] != 0;    // int32 layout
    else if (tag == 0x01010101u) valid = mask[clip] != 0;                  // byte layout
    else                         valid = ((const float*)mask)[clip] != 0.f;// float layout
    score[clip] = valid ? val : -INFINITY;
  }
}

// ---------------------------------------------------------------------------
// Kernel 3: per-batch top-8 (iterative block argmax, ties -> smaller index,
// matching lax.top_k). One block per batch; each thread owns 8 scores.
// ---------------------------------------------------------------------------
__global__ __launch_bounds__(256) void topk_kernel(
    const float* __restrict__ score, int* __restrict__ topidx) {
  int b = blockIdx.x;
  int t = threadIdx.x;
  float v[8];
  for (int j = 0; j < 8; ++j) v[j] = score[b * N_ + j * 256 + t];
  __shared__ float sv[256];
  __shared__ int   si[256];
  __shared__ int   chosen_s;
  for (int k = 0; k < TOPK_; ++k) {
    float bv = -INFINITY;
    int bi = N_;
    for (int j = 0; j < 8; ++j) {
      int e = j * 256 + t;
      if (v[j] > bv || (v[j] == bv && e < bi)) { bv = v[j]; bi = e; }
    }
    sv[t] = bv; si[t] = bi;
    __syncthreads();
    for (int s = 128; s > 0; s >>= 1) {
      if (t < s) {
        float ov = sv[t + s]; int oi = si[t + s];
        if (ov > sv[t] || (ov == sv[t] && oi < si[t])) { sv[t] = ov; si[t] = oi; }
      }
      __syncthreads();
    }
    if (t == 0) { chosen_s = si[0]; topidx[b * TOPK_ + k] = si[0]; }
    __syncthreads();
    int ch = chosen_s;
    if ((ch & 255) == t) v[ch >> 8] = -INFINITY;  // owner removes it
    __syncthreads();
  }
}

// ---------------------------------------------------------------------------
// Kernel 4: for the 8 selected clips per batch, recompute LN + full 128-class
// logits and average. One block per batch; ~67 MFLOP total, negligible.
// ---------------------------------------------------------------------------
__global__ __launch_bounds__(256) void final_kernel(
    const float* __restrict__ x, const float* __restrict__ ln_w,
    const float* __restrict__ ln_b, const float* __restrict__ W,
    const float* __restrict__ bias, const int* __restrict__ topidx,
    float* __restrict__ out) {
  int b = blockIdx.x;
  int t = threadIdx.x;
  __shared__ float xs[D_];
  __shared__ float red[256];
  __shared__ float stats[2];
  float acc = 0.f;
  for (int k = 0; k < TOPK_; ++k) {
    int n = topidx[b * TOPK_ + k];
    const float* xp = x + ((size_t)b * N_ + n) * D_;
    float lsum = 0.f, lsq = 0.f;
    for (int d = t; d < D_; d += 256) {
      float xv = xp[d];
      xs[d] = xv;
      lsum += xv;
      lsq = fmaf(xv, xv, lsq);
    }
    red[t] = lsum;
    __syncthreads();
    for (int s = 128; s > 0; s >>= 1) { if (t < s) red[t] += red[t + s]; __syncthreads(); }
    if (t == 0) stats[0] = red[0] * (1.f / D_);
    __syncthreads();
    red[t] = lsq;
    __syncthreads();
    for (int s = 128; s > 0; s >>= 1) { if (t < s) red[t] += red[t + s]; __syncthreads(); }
    if (t == 0) {
      float mu = stats[0];
      float var = red[0] * (1.f / D_) - mu * mu;
      stats[1] = rsqrtf(var + LN_EPS_);
    }
    __syncthreads();
    float mu = stats[0], rstd = stats[1];
    for (int d = t; d < D_; d += 256)
      xs[d] = fmaf((xs[d] - mu) * rstd, ln_w[d], ln_b[d]);
    __syncthreads();
    if (t < C_) {
      float dot = 0.f;
      for (int d = 0; d < D_; ++d)
        dot = fmaf(xs[d], W[d * C_ + t], dot);   // W row access is coalesced
      acc += dot + bias[t];
    }
    __syncthreads();
  }
  if (t < C_) out[(size_t)b * C_ + t] = acc * (1.f / TOPK_);
}

// ---------------------------------------------------------------------------
extern "C" void kernel_launch(void* const* d_in, const int* in_sizes, int n_in,
                              void* d_out, int out_size, void* d_ws, size_t ws_size,
                              hipStream_t stream) {
  const float* x    = (const float*)d_in[0];
  const float* ln_w = (const float*)d_in[1];
  const float* ln_b = (const float*)d_in[2];
  const float* W    = (const float*)d_in[3];
  const float* bias = (const float*)d_in[4];
  const unsigned char* mask = (const unsigned char*)d_in[5];
  const int* y      = (const int*)d_in[6];
  float* out = (float*)d_out;

  char* ws = (char*)d_ws;
  float* cw    = (float*)ws;  ws += (size_t)B_ * D_ * sizeof(float);   // 128 KB
  float* cb    = (float*)ws;  ws += (size_t)B_ * sizeof(float);
  float* su    = (float*)ws;  ws += (size_t)B_ * sizeof(float);
  float* score = (float*)ws;  ws += (size_t)B_ * N_ * sizeof(float);   // 512 KB
  int*   tidx  = (int*)ws;                                             // 2 KB

  prep_kernel<<<B_, 256, 0, stream>>>(ln_w, ln_b, W, bias, y, cw, cb, su);
  score_kernel<<<(B_ * N_) / 4, 256, 0, stream>>>(x, cw, cb, su, mask, score);
  topk_kernel<<<B_, 256, 0, stream>>>(score, tidx);
  final_kernel<<<B_, 256, 0, stream>>>(x, ln_w, ln_b, W, bias, tidx, out);
}

// Round 2
// 68.197 us; speedup vs baseline: 1.8648x; 1.8648x over previous
//
#include <hip/hip_runtime.h>
#include <math.h>

// Problem constants (from reference)
#define B_    64
#define N_    2048
#define D_    512
#define C_    128
#define TOPK_ 8
#define LN_EPS_ 1e-5f

// ---------------------------------------------------------------------------
// Mask layout auto-detect: lengths >= TOPK guarantees mask[0..7] all-true,
// so the first 32-bit word discriminates int32 / uint8 / float layouts.
// ---------------------------------------------------------------------------
__device__ __forceinline__ bool mask_valid(const unsigned char* mask, int clip) {
  unsigned int tag = *(const unsigned int*)mask;
  if (tag == 1u)               return ((const int*)mask)[clip] != 0;     // int32
  else if (tag == 0x01010101u) return mask[clip] != 0;                   // bytes
  else                         return ((const float*)mask)[clip] != 0.f; // float
}

// ---------------------------------------------------------------------------
// Kernel 1: per-batch precompute.
//   cw[b][d] = ln_w[d] * W[d, y[b]]
//   cb[b]    = sum_d ln_b[d]*W[d,y[b]] + bias[y[b]]
//   su[b]    = sum_d cw[b][d]
// ---------------------------------------------------------------------------
__global__ __launch_bounds__(256) void prep_kernel(
    const float* __restrict__ ln_w, const float* __restrict__ ln_b,
    const float* __restrict__ W, const float* __restrict__ bias,
    const int* __restrict__ y,
    float* __restrict__ cw, float* __restrict__ cb, float* __restrict__ su) {
  int b = blockIdx.x;
  int cls = y[b];
  __shared__ float red0[256];
  __shared__ float red1[256];
  float l0 = 0.f, l1 = 0.f;
  for (int d = threadIdx.x; d < D_; d += 256) {
    float wcol = W[d * C_ + cls];
    float u = ln_w[d] * wcol;
    cw[b * D_ + d] = u;
    l0 += ln_b[d] * wcol;
    l1 += u;
  }
  red0[threadIdx.x] = l0;
  red1[threadIdx.x] = l1;
  __syncthreads();
  for (int s = 128; s > 0; s >>= 1) {
    if (threadIdx.x < s) {
      red0[threadIdx.x] += red0[threadIdx.x + s];
      red1[threadIdx.x] += red1[threadIdx.x + s];
    }
    __syncthreads();
  }
  if (threadIdx.x == 0) {
    cb[b] = red0[0] + bias[cls];
    su[b] = red1[0];
  }
}

// ---------------------------------------------------------------------------
// Kernel 2 (HBM-bound): one wave per clip. EARLY-EXIT on invalid clips so
// their x rows are never fetched (~50% of traffic skipped on average).
// Valid clips: fused sum(x), sum(x^2), dot(x, cw) in one pass, shfl reduce.
// ---------------------------------------------------------------------------
__global__ __launch_bounds__(256) void score_kernel(
    const float* __restrict__ x, const float* __restrict__ cw,
    const float* __restrict__ cb, const float* __restrict__ su,
    const unsigned char* __restrict__ mask, float* __restrict__ score) {
  int wave = threadIdx.x >> 6;
  int lane = threadIdx.x & 63;
  int clip = blockIdx.x * 4 + wave;          // 0 .. B*N-1
  int b = clip >> 11;                        // clip / N_

  if (!mask_valid(mask, clip)) {             // wave-uniform branch
    if (lane == 0) score[clip] = -INFINITY;
    return;
  }

  const float4* x4 = (const float4*)(x + (size_t)clip * D_);
  const float4* u4 = (const float4*)(cw + (size_t)b * D_);
  float4 xa = x4[lane];
  float4 xb = x4[lane + 64];
  float4 ua = u4[lane];
  float4 ub = u4[lane + 64];
  float s  = xa.x + xa.y + xa.z + xa.w + xb.x + xb.y + xb.z + xb.w;
  float sq = fmaf(xa.x, xa.x, fmaf(xa.y, xa.y, fmaf(xa.z, xa.z, xa.w * xa.w)))
           + fmaf(xb.x, xb.x, fmaf(xb.y, xb.y, fmaf(xb.z, xb.z, xb.w * xb.w)));
  float dt = fmaf(xa.x, ua.x, fmaf(xa.y, ua.y, fmaf(xa.z, ua.z, xa.w * ua.w)))
           + fmaf(xb.x, ub.x, fmaf(xb.y, ub.y, fmaf(xb.z, ub.z, xb.w * ub.w)));
  for (int off = 32; off > 0; off >>= 1) {
    s  += __shfl_xor(s, off);
    sq += __shfl_xor(sq, off);
    dt += __shfl_xor(dt, off);
  }
  if (lane == 0) {
    float mu = s * (1.f / D_);
    float var = sq * (1.f / D_) - mu * mu;
    float rstd = rsqrtf(var + LN_EPS_);
    score[clip] = rstd * (dt - mu * su[b]) + cb[b];
  }
}

// ---------------------------------------------------------------------------
// Kernel 3: per-batch top-8, ONE WAVE per batch, shfl-only (no barriers).
// Ties -> smaller index (matches lax.top_k). 4 batches per 256-thread block.
// ---------------------------------------------------------------------------
__global__ __launch_bounds__(256) void topk_kernel(
    const float* __restrict__ score, int* __restrict__ topidx) {
  int wave = threadIdx.x >> 6;
  int lane = threadIdx.x & 63;
  int b = blockIdx.x * 4 + wave;
  float v[32];                                // N_/64 = 32 scores per lane
  for (int j = 0; j < 32; ++j) v[j] = score[b * N_ + j * 64 + lane];
  for (int k = 0; k < TOPK_; ++k) {
    float bv = -INFINITY;
    int bi = N_;
    for (int j = 0; j < 32; ++j) {
      int e = j * 64 + lane;
      if (v[j] > bv || (v[j] == bv && e < bi)) { bv = v[j]; bi = e; }
    }
    for (int off = 32; off > 0; off >>= 1) {
      float ov = __shfl_xor(bv, off);
      int   oi = __shfl_xor(bi, off);
      if (ov > bv || (ov == bv && oi < bi)) { bv = ov; bi = oi; }
    }
    // bv/bi now uniform across the wave
    if (lane == 0) topidx[b * TOPK_ + k] = bi;
    if ((bi & 63) == lane) v[bi >> 6] = -INFINITY;   // owner removes it
  }
}

// ---------------------------------------------------------------------------
// Kernel 4: one block per selected clip (B*TOPK = 512 blocks). LN + full
// 128-class logits -> sel[b][k][C].
// ---------------------------------------------------------------------------
__global__ __launch_bounds__(256) void final_kernel(
    const float* __restrict__ x, const float* __restrict__ ln_w,
    const float* __restrict__ ln_b, const float* __restrict__ W,
    const float* __restrict__ bias, const int* __restrict__ topidx,
    float* __restrict__ sel) {
  int b = blockIdx.x >> 3;
  int k = blockIdx.x & 7;
  int t = threadIdx.x;
  int n = topidx[b * TOPK_ + k];
  __shared__ float xs[D_];
  __shared__ float red[256];
  __shared__ float stats[2];
  const float4* xp4 = (const float4*)(x + ((size_t)b * N_ + n) * D_);
  float lsum = 0.f, lsq = 0.f;
  if (t < 128) {                               // 128 float4 = 512 floats
    float4 xv = xp4[t];
    ((float4*)xs)[t] = xv;
    lsum = xv.x + xv.y + xv.z + xv.w;
    lsq = fmaf(xv.x, xv.x, fmaf(xv.y, xv.y, fmaf(xv.z, xv.z, xv.w * xv.w)));
  }
  red[t] = lsum;
  __syncthreads();
  for (int s = 128; s > 0; s >>= 1) { if (t < s) red[t] += red[t + s]; __syncthreads(); }
  if (t == 0) stats[0] = red[0] * (1.f / D_);
  __syncthreads();
  red[t] = lsq;
  __syncthreads();
  for (int s = 128; s > 0; s >>= 1) { if (t < s) red[t] += red[t + s]; __syncthreads(); }
  if (t == 0) {
    float mu = stats[0];
    float var = red[0] * (1.f / D_) - mu * mu;
    stats[1] = rsqrtf(var + LN_EPS_);
  }
  __syncthreads();
  float mu = stats[0], rstd = stats[1];
  for (int d = t; d < D_; d += 256)
    xs[d] = fmaf((xs[d] - mu) * rstd, ln_w[d], ln_b[d]);
  __syncthreads();
  if (t < C_) {
    float dot = 0.f;
    for (int d = 0; d < D_; ++d)
      dot = fmaf(xs[d], W[d * C_ + t], dot);   // xs broadcast; W coalesced
    sel[((size_t)b * TOPK_ + k) * C_ + t] = dot + bias[t];
  }
}

// ---------------------------------------------------------------------------
// Kernel 5: average the 8 selected-clip logit rows per batch.
// ---------------------------------------------------------------------------
__global__ __launch_bounds__(128) void avg_kernel(
    const float* __restrict__ sel, float* __restrict__ out) {
  int b = blockIdx.x;
  int t = threadIdx.x;
  float acc = 0.f;
  for (int k = 0; k < TOPK_; ++k)
    acc += sel[((size_t)b * TOPK_ + k) * C_ + t];
  out[(size_t)b * C_ + t] = acc * (1.f / TOPK_);
}

// ---------------------------------------------------------------------------
extern "C" void kernel_launch(void* const* d_in, const int* in_sizes, int n_in,
                              void* d_out, int out_size, void* d_ws, size_t ws_size,
                              hipStream_t stream) {
  const float* x    = (const float*)d_in[0];
  const float* ln_w = (const float*)d_in[1];
  const float* ln_b = (const float*)d_in[2];
  const float* W    = (const float*)d_in[3];
  const float* bias = (const float*)d_in[4];
  const unsigned char* mask = (const unsigned char*)d_in[5];
  const int* y      = (const int*)d_in[6];
  float* out = (float*)d_out;

  char* ws = (char*)d_ws;
  float* cw    = (float*)ws;  ws += (size_t)B_ * D_ * sizeof(float);        // 128 KB
  float* cb    = (float*)ws;  ws += (size_t)B_ * sizeof(float);
  float* su    = (float*)ws;  ws += (size_t)B_ * sizeof(float);
  float* score = (float*)ws;  ws += (size_t)B_ * N_ * sizeof(float);        // 512 KB
  int*   tidx  = (int*)ws;    ws += (size_t)B_ * TOPK_ * sizeof(int);       // 2 KB
  float* sel   = (float*)ws;                                                // 256 KB

  prep_kernel <<<B_, 256, 0, stream>>>(ln_w, ln_b, W, bias, y, cw, cb, su);
  score_kernel<<<(B_ * N_) / 4, 256, 0, stream>>>(x, cw, cb, su, mask, score);
  topk_kernel <<<B_ / 4, 256, 0, stream>>>(score, tidx);
  final_kernel<<<B_ * TOPK_, 256, 0, stream>>>(x, ln_w, ln_b, W, bias, tidx, sel);
  avg_kernel  <<<B_, 128, 0, stream>>>(sel, out);
}